// Round 1
// baseline (715.189 us; speedup 1.0000x reference)
//
#include <hip/hip_runtime.h>

// CRF classifier: emissions GEMM + forward (loss) + viterbi (+backtrace).
// Shapes fixed: B=64, T=512, H=768, L=32.
constexpr int Bn = 64, Tn = 512, Hn = 768, Ln = 32;
constexpr int BT = Bn * Tn;               // 32768 rows
constexpr int EM_FLOATS = BT * Ln;        // 1M floats = 4 MB in ws

// ---------------- emissions = hs @ W + b  (f32, vector ALU) ----------------
// 256 blocks x 256 threads; block tile = 128 rows x 32 cols; thread = 4r x 4c.
// W staged in LDS in two 384-row halves (48 KB), broadcast b128 reads.
__global__ __launch_bounds__(256) void emis_gemm(const float* __restrict__ hs,
                                                 const float* __restrict__ W,
                                                 const float* __restrict__ bias,
                                                 float* __restrict__ em) {
  __shared__ __align__(16) float wbuf[384 * Ln];
  const int tid = threadIdx.x;
  const int row0 = blockIdx.x * 128;
  const int cg = tid & 7, rg = tid >> 3;
  const int c0 = cg * 4;
  float4 acc[4];
#pragma unroll
  for (int i = 0; i < 4; ++i) acc[i] = make_float4(0.f, 0.f, 0.f, 0.f);
  for (int kh = 0; kh < 2; ++kh) {
    const float4* wg = (const float4*)(W + kh * 384 * Ln);
#pragma unroll
    for (int it = 0; it < 12; ++it) ((float4*)wbuf)[it * 256 + tid] = wg[it * 256 + tid];
    __syncthreads();
    const float* hb = hs + (long)(row0 + rg * 4) * Hn + kh * 384;
    for (int k4 = 0; k4 < 384; k4 += 4) {
      float4 h[4];
#pragma unroll
      for (int i = 0; i < 4; ++i) h[i] = *(const float4*)(hb + (long)i * Hn + k4);
#pragma unroll
      for (int kk = 0; kk < 4; ++kk) {
        float4 wv = *(const float4*)&wbuf[(k4 + kk) * Ln + c0];
#pragma unroll
        for (int i = 0; i < 4; ++i) {
          float hv = kk == 0 ? h[i].x : kk == 1 ? h[i].y : kk == 2 ? h[i].z : h[i].w;
          acc[i].x = fmaf(hv, wv.x, acc[i].x);
          acc[i].y = fmaf(hv, wv.y, acc[i].y);
          acc[i].z = fmaf(hv, wv.z, acc[i].z);
          acc[i].w = fmaf(hv, wv.w, acc[i].w);
        }
      }
    }
    __syncthreads();
  }
  float4 bv = *(const float4*)&bias[c0];
#pragma unroll
  for (int i = 0; i < 4; ++i) {
    float4 o = make_float4(acc[i].x + bv.x, acc[i].y + bv.y, acc[i].z + bv.z, acc[i].w + bv.w);
    *(float4*)&em[(long)(row0 + rg * 4 + i) * Ln + c0] = o;
  }
}

// ---------------- forward + viterti scans, one wave per batch ----------------
// grid = 128 blocks x 64 threads. blocks [0,64): forward(+numer); [64,128): viterbi.
__global__ __launch_bounds__(64) void crf_scan(const float* __restrict__ em,
                                               const int* __restrict__ mask,
                                               const int* __restrict__ labels,
                                               const float* __restrict__ startT,
                                               const float* __restrict__ endT,
                                               const float* __restrict__ trans,
                                               float* __restrict__ nd,
                                               float* __restrict__ outp) {
  const int lane = threadIdx.x;
  const int j = lane & 31;
  const int bid = blockIdx.x & 63;
  const bool is_vit = blockIdx.x >= 64;

  // sequence length (mask is monotone: arange < length)
  int s = 0;
  for (int t = lane; t < Tn; t += 64) s += mask[bid * Tn + t];
#pragma unroll
  for (int m = 1; m <= 32; m <<= 1) s += __shfl_xor(s, m);
  const int len = s;  // in [256, 512]
  const float* emb = em + (long)bid * Tn * Ln;

  if (!is_vit) {
    // ------------- forward (log-domain, shift by score[0]) -------------
    __shared__ __align__(16) float e_lds[32];
    float et[32];
#pragma unroll
    for (int i = 0; i < 32; ++i) et[i] = __expf(trans[i * Ln + j]);
    float score = startT[j] + emb[j];
    float emn = emb[Ln + j];
    for (int t = 1; t < len; ++t) {
      float em_t = emn;
      int tn = t + 1 < Tn ? t + 1 : Tn - 1;
      emn = emb[tn * Ln + j];                 // prefetch next row
      float s0 = __shfl(score, 0);            // any shift is exact LSE algebra
      float e = __expf(score - s0);           // bounded: score spread <~ 8
      if (lane < 32) e_lds[j] = e;
      float a0 = 0.f, a1 = 0.f, a2 = 0.f, a3 = 0.f;
#pragma unroll
      for (int q = 0; q < 8; ++q) {
        float4 ev = *(float4*)&e_lds[q * 4];  // broadcast read
        a0 = fmaf(ev.x, et[q * 4 + 0], a0);
        a1 = fmaf(ev.y, et[q * 4 + 1], a1);
        a2 = fmaf(ev.z, et[q * 4 + 2], a2);
        a3 = fmaf(ev.w, et[q * 4 + 3], a3);
      }
      score = s0 + __logf((a0 + a1) + (a2 + a3)) + em_t;
    }
    // denom = LSE_j(score + end)
    float v = score + endT[j];
    float mx = v;
#pragma unroll
    for (int m = 1; m <= 16; m <<= 1) mx = fmaxf(mx, __shfl_xor(mx, m));
    float ssum = __expf(v - mx);
#pragma unroll
    for (int m = 1; m <= 16; m <<= 1) ssum += __shfl_xor(ssum, m);
    float denom = mx + __logf(ssum);
    // numer (gold-path score), parallel over t
    float part = 0.f;
    const int* lab = labels + bid * Tn;
    for (int t = lane; t < Tn; t += 64) {
      int lt = lab[t];
      if (t == 0)
        part += startT[lt] + emb[lt];
      else if (t < len)
        part += emb[t * Ln + lt] + trans[lab[t - 1] * Ln + lt];
    }
#pragma unroll
    for (int m = 1; m <= 32; m <<= 1) part += __shfl_xor(part, m);
    if (lane == 0) {
      int lastl = lab[len - 1];
      nd[bid] = part + endT[lastl] - denom;
    }
  } else {
    // ------------- viterbi + parallel backtrace -------------
    __shared__ unsigned short hist[Tn * Ln];  // 32 KB backpointers (identity-patched)
    __shared__ __align__(16) float sc_lds[32];
    __shared__ int Ctab[32 * 32];
    __shared__ int bnd[33];
    const int half = lane >> 5;
    float tr16[16];
#pragma unroll
    for (int q = 0; q < 16; ++q) tr16[q] = trans[(half * 16 + q) * Ln + j];
    float score = startT[j] + emb[j];
    float emn = emb[Ln + j];
    for (int t = 1; t < len; ++t) {
      float em_t = emn;
      int tn = t + 1 < Tn ? t + 1 : Tn - 1;
      emn = emb[tn * Ln + j];
      if (lane < 32) sc_lds[j] = score;
      float v[16];
      int id[16];
#pragma unroll
      for (int q4 = 0; q4 < 4; ++q4) {
        float4 s4 = *(float4*)&sc_lds[half * 16 + q4 * 4];
        v[q4 * 4 + 0] = s4.x + tr16[q4 * 4 + 0];
        v[q4 * 4 + 1] = s4.y + tr16[q4 * 4 + 1];
        v[q4 * 4 + 2] = s4.z + tr16[q4 * 4 + 2];
        v[q4 * 4 + 3] = s4.w + tr16[q4 * 4 + 3];
      }
#pragma unroll
      for (int q = 0; q < 16; ++q) id[q] = half * 16 + q;
      // first-index argmax tournament (exact tie rule: smaller index wins)
#pragma unroll
      for (int sz = 8; sz >= 1; sz >>= 1) {
#pragma unroll
        for (int q = 0; q < sz; ++q) {
          bool tk = (v[q + sz] > v[q]) || (v[q + sz] == v[q] && id[q + sz] < id[q]);
          if (tk) { v[q] = v[q + sz]; id[q] = id[q + sz]; }
        }
      }
      float ov = __shfl_xor(v[0], 32);
      int oi = __shfl_xor(id[0], 32);
      bool tk = (ov > v[0]) || (ov == v[0] && oi < id[0]);
      float mv = tk ? ov : v[0];
      int mi = tk ? oi : id[0];
      if (lane < 32) hist[(t - 1) * Ln + j] = (unsigned short)mi;
      score = mv + em_t;
    }
    // identity-patch rows [len-1, 511] (masked steps; row 511 bridges fake pos 512)
    for (int x = lane; x < (Tn - (len - 1)) * Ln; x += 64) {
      int r = len - 1 + (x >> 5);
      int c = x & 31;
      hist[r * Ln + c] = (unsigned short)c;
    }
    // best_last = first-index argmax_j(score + end)
    float bv = score + endT[j];
    int bj = j;
#pragma unroll
    for (int m = 1; m <= 16; m <<= 1) {
      float ov2 = __shfl_xor(bv, m);
      int oi2 = __shfl_xor(bj, m);
      if (ov2 > bv || (ov2 == bv && oi2 < bj)) { bv = ov2; bj = oi2; }
    }
    const int best_last = bj;
    __syncthreads();
    // phase 1: compose 32 chunks of 16 backpointer maps (parallel chains)
    int F[16];
    const int kh2 = half;
#pragma unroll
    for (int kk = 0; kk < 16; ++kk) F[kk] = hist[(16 * (kh2 * 16 + kk) + 15) * Ln + j];
    for (int s2 = 14; s2 >= 0; --s2) {
#pragma unroll
      for (int kk = 0; kk < 16; ++kk) F[kk] = hist[(16 * (kh2 * 16 + kk) + s2) * Ln + F[kk]];
    }
#pragma unroll
    for (int kk = 0; kk < 16; ++kk) Ctab[(kh2 * 16 + kk) * 32 + j] = F[kk];
    __syncthreads();
    // phase 2: boundary carries across 32 chunks (sequential, 1 lane)
    if (lane == 0) {
      int c = best_last;
      bnd[32] = c;
      for (int k = 31; k >= 0; --k) {
        c = Ctab[k * 32 + c];
        bnd[k] = c;
      }
    }
    __syncthreads();
    // phase 3: lanes replay their chunk, write predictions
    if (lane < 32) {
      int k = lane;
      int c = bnd[k + 1];
      float* po = outp + 1 + (long)bid * Tn;
#pragma unroll
      for (int s3 = 15; s3 >= 0; --s3) {
        int t = 16 * k + s3;
        c = hist[t * Ln + c];
        po[t] = (t < len) ? (float)c : 0.0f;  // PAD = 0 beyond last_idx
      }
    }
  }
}

// ---------------- loss = -sum(numer - denom) ----------------
__global__ __launch_bounds__(64) void loss_reduce(const float* __restrict__ nd,
                                                  float* __restrict__ outp) {
  float v = nd[threadIdx.x];
#pragma unroll
  for (int m = 1; m <= 32; m <<= 1) v += __shfl_xor(v, m);
  if (threadIdx.x == 0) outp[0] = -v;
}

extern "C" void kernel_launch(void* const* d_in, const int* in_sizes, int n_in,
                              void* d_out, int out_size, void* d_ws, size_t ws_size,
                              hipStream_t stream) {
  const float* hs = (const float*)d_in[0];      // (64,512,768) f32
  const int* mask = (const int*)d_in[1];        // (64,512) i32
  const int* labels = (const int*)d_in[2];      // (64,512) i32
  const float* W = (const float*)d_in[3];       // (768,32) f32
  const float* b = (const float*)d_in[4];       // (32,) f32
  const float* startT = (const float*)d_in[5];  // (32,)
  const float* endT = (const float*)d_in[6];    // (32,)
  const float* trans = (const float*)d_in[7];   // (32,32)
  float* out = (float*)d_out;                   // [loss, pred_labels(64*512)] as f32
  float* em = (float*)d_ws;                     // 4 MB emissions
  float* nd = em + EM_FLOATS;                   // 64 per-batch (numer - denom)

  emis_gemm<<<256, 256, 0, stream>>>(hs, W, b, em);
  crf_scan<<<128, 64, 0, stream>>>(em, mask, labels, startT, endT, trans, nd, out);
  loss_reduce<<<1, 64, 0, stream>>>(nd, out);
}

// Round 2
// 406.127 us; speedup vs baseline: 1.7610x; 1.7610x over previous
//
#include <hip/hip_runtime.h>

// CRF classifier: emissions GEMM + forward (loss) + viterbi (+backtrace).
// Shapes fixed: B=64, T=512, H=768, L=32.
constexpr int Bn = 64, Tn = 512, Hn = 768, Ln = 32;

// ---------------- emissions = hs @ W + b  (f32, vector ALU) ----------------
// 256 blocks x 256 threads. Block = 128 rows. Thread = 1 row x 32 cols x K-half.
// W (96 KB) fully staged in LDS; hs read exactly once (96 MB total).
__global__ __launch_bounds__(256) void emis_gemm(const float* __restrict__ hs,
                                                 const float* __restrict__ W,
                                                 const float* __restrict__ bias,
                                                 float* __restrict__ em) {
  __shared__ __align__(16) float4 wl[Hn * 8];    // 96 KB: wl[k*8 + c4]
  __shared__ __align__(16) float4 cbuf[128 * 8]; // 16 KB partial-sum combine
  const int tid = threadIdx.x;
  for (int it = tid; it < Hn * 8; it += 256) wl[it] = ((const float4*)W)[it];
  __syncthreads();
  const int half = tid >> 7;      // K half: [0,384) or [384,768)
  const int r = tid & 127;        // local row
  const long row = (long)blockIdx.x * 128 + r;
  const float* hb = hs + row * Hn + half * 384;
  const float4* wp = wl + half * 384 * 8;
  float4 acc[8];
#pragma unroll
  for (int c = 0; c < 8; ++c) acc[c] = make_float4(0.f, 0.f, 0.f, 0.f);
  for (int k4 = 0; k4 < 384; k4 += 4) {
    float4 h = *(const float4*)(hb + k4);
#pragma unroll
    for (int kk = 0; kk < 4; ++kk) {
      float hv = kk == 0 ? h.x : kk == 1 ? h.y : kk == 2 ? h.z : h.w;
      const float4* wr = wp + (k4 + kk) * 8;
#pragma unroll
      for (int c = 0; c < 8; ++c) {
        float4 wv = wr[c];
        acc[c].x = fmaf(hv, wv.x, acc[c].x);
        acc[c].y = fmaf(hv, wv.y, acc[c].y);
        acc[c].z = fmaf(hv, wv.z, acc[c].z);
        acc[c].w = fmaf(hv, wv.w, acc[c].w);
      }
    }
  }
  if (half == 1) {
#pragma unroll
    for (int c = 0; c < 8; ++c) cbuf[r * 8 + c] = acc[c];
  }
  __syncthreads();
  if (half == 0) {
#pragma unroll
    for (int c = 0; c < 8; ++c) {
      float4 p = cbuf[r * 8 + c];
      float4 bv = ((const float4*)bias)[c];
      float4 o = make_float4(acc[c].x + p.x + bv.x, acc[c].y + p.y + bv.y,
                             acc[c].z + p.z + bv.z, acc[c].w + p.w + bv.w);
      *(float4*)(em + row * Ln + c * 4) = o;
    }
  }
}

// ---------------- forward + viterbi scans + backtrace ----------------
// 8 blocks x 512 threads (8 waves). Waves 0-3: viterbi (2 batches/wave);
// waves 4-7: forward (2 batches/wave). Each SIMD hosts 1 vit + 1 fwd wave
// (mutual latency hiding). Then all 8 waves each backtrace one batch.
__global__ __launch_bounds__(512) void crf_scan(const float* __restrict__ em,
                                                const int* __restrict__ mask,
                                                const int* __restrict__ labels,
                                                const float* __restrict__ startT,
                                                const float* __restrict__ endT,
                                                const float* __restrict__ trans,
                                                float* __restrict__ outp) {
  __shared__ unsigned char hist[8][Tn][Ln];        // 128 KB backpointers (u8)
  __shared__ __align__(16) float stage[8][64];     // per-wave broadcast buffers
  __shared__ unsigned char Ctab[8][32][32];        // chunk-composition tables
  __shared__ int bnd[8][33];
  __shared__ int bl_lds[8];
  __shared__ int len_lds[8];

  const int tid = threadIdx.x;
  const int wid = tid >> 6;
  const int lane = tid & 63;
  const int half = lane >> 5;
  const int j = lane & 31;
  const bool is_vit = wid < 4;
  const int wb = ((wid & 3) << 1) + half;          // local batch index 0..7
  const int batch = blockIdx.x * 8 + wb;

  // sequence length of this lane's batch (mask monotone)
  int s = 0;
  for (int t = j; t < Tn; t += 32) s += mask[batch * Tn + t];
#pragma unroll
  for (int m = 1; m <= 16; m <<= 1) s += __shfl_xor(s, m);
  const int len = s;                                // in [256, 512]
  const int lw = max(len, __shfl_xor(len, 32));     // wave loop bound
  const float* emb = em + (long)batch * Tn * Ln;

  if (is_vit) {
    if (j == 0) len_lds[wb] = len;
    float tr[32];
#pragma unroll
    for (int i = 0; i < 32; ++i) tr[i] = trans[i * Ln + j];
    float score = startT[j] + emb[j];
    float emn = emb[Ln + j];
    for (int t = 1; t < lw; ++t) {
      float em_t = emn;
      int tn = t + 1 < Tn ? t + 1 : Tn - 1;
      emn = emb[tn * Ln + j];
      stage[wid][lane] = score;                     // same-wave LDS broadcast
      const float* sb = &stage[wid][half * 32];
      float v[32];
#pragma unroll
      for (int q4 = 0; q4 < 8; ++q4) {
        float4 s4 = *(const float4*)(sb + q4 * 4);
        v[q4 * 4 + 0] = s4.x + tr[q4 * 4 + 0];
        v[q4 * 4 + 1] = s4.y + tr[q4 * 4 + 1];
        v[q4 * 4 + 2] = s4.z + tr[q4 * 4 + 2];
        v[q4 * 4 + 3] = s4.w + tr[q4 * 4 + 3];
      }
      // exact max via tree (fuses to v_max3); argmax off critical path
      float w[16];
#pragma unroll
      for (int q = 0; q < 16; ++q) w[q] = fmaxf(v[q], v[q + 16]);
#pragma unroll
      for (int sz = 8; sz >= 1; sz >>= 1)
#pragma unroll
        for (int q = 0; q < sz; ++q) w[q] = fmaxf(w[q], w[q + sz]);
      const float mv = w[0];
      int mi = 31;
#pragma unroll
      for (int i = 31; i >= 0; --i) mi = (v[i] == mv) ? i : mi;  // first max
      hist[wb][t - 1][j] = (unsigned char)mi;
      score = (t < len) ? (mv + em_t) : score;
    }
    // identity-patch rows [len-1, 511]
    for (int x = j; x < (Tn + 1 - len) * Ln; x += 32) {
      int rr = len - 1 + (x >> 5);
      hist[wb][rr][x & 31] = (unsigned char)(x & 31);
    }
    // best_last: first-index argmax of (score + end)
    float bv = score + endT[j];
    int bj = j;
#pragma unroll
    for (int m = 1; m <= 16; m <<= 1) {
      float ov = __shfl_xor(bv, m);
      int oi = __shfl_xor(bj, m);
      if (ov > bv || (ov == bv && oi < bj)) { bv = ov; bj = oi; }
    }
    if (j == 0) bl_lds[wb] = bj;
  } else {
    // ---------------- forward (log-domain, shift by batch lane-0 score) -----
    float et[32];
#pragma unroll
    for (int i = 0; i < 32; ++i) et[i] = __expf(trans[i * Ln + j]);
    float score = startT[j] + emb[j];
    float emn = emb[Ln + j];
    for (int t = 1; t < lw; ++t) {
      float em_t = emn;
      int tn = t + 1 < Tn ? t + 1 : Tn - 1;
      emn = emb[tn * Ln + j];
      float s0 = __shfl(score, lane & 32);          // per-batch uniform shift
      float e = __expf(score - s0);
      stage[wid][lane] = e;
      const float* eb = &stage[wid][half * 32];
      float a0 = 0.f, a1 = 0.f, a2 = 0.f, a3 = 0.f;
#pragma unroll
      for (int q = 0; q < 8; ++q) {
        float4 ev = *(const float4*)(eb + q * 4);
        a0 = fmaf(ev.x, et[q * 4 + 0], a0);
        a1 = fmaf(ev.y, et[q * 4 + 1], a1);
        a2 = fmaf(ev.z, et[q * 4 + 2], a2);
        a3 = fmaf(ev.w, et[q * 4 + 3], a3);
      }
      float nx = s0 + __logf((a0 + a1) + (a2 + a3)) + em_t;
      score = (t < len) ? nx : score;
    }
    // denom = LSE_j(score + end), within 32-lane half
    float v = score + endT[j];
    float mx = v;
#pragma unroll
    for (int m = 1; m <= 16; m <<= 1) mx = fmaxf(mx, __shfl_xor(mx, m));
    float ssum = __expf(v - mx);
#pragma unroll
    for (int m = 1; m <= 16; m <<= 1) ssum += __shfl_xor(ssum, m);
    float denom = mx + __logf(ssum);
    // numer (gold-path score), strided over the half's 32 lanes
    float part = 0.f;
    const int* lab = labels + batch * Tn;
    for (int t = j; t < Tn; t += 32) {
      int lt = lab[t];
      if (t == 0)
        part += startT[lt] + emb[lt];
      else if (t < len)
        part += emb[t * Ln + lt] + trans[lab[t - 1] * Ln + lt];
    }
#pragma unroll
    for (int m = 1; m <= 16; m <<= 1) part += __shfl_xor(part, m);
    if (j == 0) {
      int lastl = lab[len - 1];
      atomicAdd(outp, denom - (part + endT[lastl]));  // loss contribution
    }
  }
  __syncthreads();

  // ---------------- parallel backtrace: wave wid -> batch wid ----------------
  {
    const int wb2 = wid;
    const int batch2 = blockIdx.x * 8 + wb2;
    const int len2 = len_lds[wb2];
    const int best_last = bl_lds[wb2];
    const int kh2 = lane >> 5;
    // phase 1: compose 32 chunks of 16 backpointer maps
    int F[16];
#pragma unroll
    for (int kk = 0; kk < 16; ++kk) F[kk] = hist[wb2][16 * (kh2 * 16 + kk) + 15][j];
    for (int s2 = 14; s2 >= 0; --s2) {
#pragma unroll
      for (int kk = 0; kk < 16; ++kk) F[kk] = hist[wb2][16 * (kh2 * 16 + kk) + s2][F[kk]];
    }
#pragma unroll
    for (int kk = 0; kk < 16; ++kk) Ctab[wb2][kh2 * 16 + kk][j] = (unsigned char)F[kk];
    __syncthreads();
    // phase 2: boundary carries (sequential, lane 0)
    if (lane == 0) {
      int c = best_last;
      bnd[wb2][32] = c;
      for (int k = 31; k >= 0; --k) {
        c = Ctab[wb2][k][c];
        bnd[wb2][k] = c;
      }
    }
    __syncthreads();
    // phase 3: 32 lanes replay their chunk, write predictions
    if (lane < 32) {
      int c = bnd[wb2][lane + 1];
      float* po = outp + 1 + (long)batch2 * Tn;
#pragma unroll
      for (int s3 = 15; s3 >= 0; --s3) {
        int t = 16 * lane + s3;
        c = hist[wb2][t][c];
        po[t] = (t < len2) ? (float)c : 0.0f;       // PAD = 0 beyond last_idx
      }
    }
  }
}

extern "C" void kernel_launch(void* const* d_in, const int* in_sizes, int n_in,
                              void* d_out, int out_size, void* d_ws, size_t ws_size,
                              hipStream_t stream) {
  const float* hs = (const float*)d_in[0];      // (64,512,768) f32
  const int* mask = (const int*)d_in[1];        // (64,512) i32
  const int* labels = (const int*)d_in[2];      // (64,512) i32
  const float* W = (const float*)d_in[3];       // (768,32) f32
  const float* b = (const float*)d_in[4];       // (32,) f32
  const float* startT = (const float*)d_in[5];  // (32,)
  const float* endT = (const float*)d_in[6];    // (32,)
  const float* trans = (const float*)d_in[7];   // (32,32)
  float* out = (float*)d_out;                   // [loss, pred_labels(64*512)] f32
  float* em = (float*)d_ws;                     // 4 MB emissions

  emis_gemm<<<256, 256, 0, stream>>>(hs, W, b, em);
  hipMemsetAsync(d_out, 0, sizeof(float), stream);  // zero loss accumulator
  crf_scan<<<8, 512, 0, stream>>>(em, mask, labels, startT, endT, trans, out);
}